// Round 1
// baseline (810.364 us; speedup 1.0000x reference)
//
#include <hip/hip_runtime.h>

typedef unsigned long long u64;

#define HW 3136      // 56*56
#define NPIX 100352  // 32*3136

// ---------------- pack weights: [co][kh][kw] -> 4 x u64 (256 ci bits) -------
__global__ __launch_bounds__(256) void pack_w_kernel(const float* __restrict__ W,
                                                     u64* __restrict__ wp) {
    int t = blockIdx.x * 256 + threadIdx.x;   // co*9 + tap, 2304 total (9 blocks)
    int co = t / 9, tap = t % 9;
    u64 b[4] = {0, 0, 0, 0};
    for (int ci = 0; ci < 256; ++ci) {
        float v = W[(size_t)(co * 256 + ci) * 9 + tap];
        if (v >= 0.f) b[ci >> 6] |= 1ull << (ci & 63);
    }
    u64* dst = wp + (size_t)t * 4;
    dst[0] = b[0]; dst[1] = b[1]; dst[2] = b[2]; dst[3] = b[3];
}

// ---------------- pack activations: [n][h][w] -> 4 x u64 --------------------
__global__ __launch_bounds__(256) void pack_x_kernel(const float* __restrict__ x,
                                                     u64* __restrict__ xp) {
    int s = blockIdx.x * 256 + threadIdx.x;   // pixel in [0, 100352)
    int word = blockIdx.y;                    // 0..3 (64 channels each)
    int n = s / HW, hw = s % HW;
    const float* px = x + (size_t)(n * 256 + word * 64) * HW + hw;
    u64 b = 0;
    #pragma unroll 8
    for (int ci = 0; ci < 64; ++ci) {
        float v = px[(size_t)ci * HW];
        if (v >= 0.f) b |= 1ull << ci;
    }
    xp[(size_t)s * 4 + word] = b;
}

// ---------------- XNOR conv + fused channel-stat reduction ------------------
__global__ __launch_bounds__(256) void conv_kernel(const u64* __restrict__ xp,
                                                   const u64* __restrict__ wp,
                                                   short* __restrict__ y,
                                                   u64* __restrict__ ssum,
                                                   u64* __restrict__ ssq) {
    int s = blockIdx.x * 256 + threadIdx.x;   // pixel
    int n = s / HW, hw = s % HW;
    int h = hw / 56, w = hw % 56;

    u64 xv[9][4];
    int mask9 = 0;
    #pragma unroll
    for (int kh = 0; kh < 3; ++kh) {
        int hh = h + 2 * kh - 2;
        int hc = hh < 0 ? 0 : (hh > 55 ? 55 : hh);
        #pragma unroll
        for (int kw = 0; kw < 3; ++kw) {
            int ww = w + 2 * kw - 2;
            int wc = ww < 0 ? 0 : (ww > 55 ? 55 : ww);
            int t = kh * 3 + kw;
            const u64* p = xp + ((size_t)(n * HW) + hc * 56 + wc) * 4;
            xv[t][0] = p[0]; xv[t][1] = p[1]; xv[t][2] = p[2]; xv[t][3] = p[3];
            if (hh == hc && ww == wc) mask9 |= 1 << t;   // in-bounds tap
        }
    }
    int base = 256 * __popc(mask9);

    int co0 = blockIdx.y * 64;
    for (int cl = 0; cl < 64; ++cl) {
        int co = co0 + cl;
        const u64* wq = wp + (size_t)co * 36;
        int pacc = 0;
        #pragma unroll
        for (int t = 0; t < 9; ++t) {
            int p = __popcll(xv[t][0] ^ wq[t * 4 + 0]) + __popcll(xv[t][1] ^ wq[t * 4 + 1])
                  + __popcll(xv[t][2] ^ wq[t * 4 + 2]) + __popcll(xv[t][3] ^ wq[t * 4 + 3]);
            pacc += ((mask9 >> t) & 1) ? p : 0;
        }
        int yv = base - 2 * pacc;                         // exact integer conv result
        y[(size_t)(n * 256 + co) * HW + hw] = (short)yv;

        int rs = yv, rq = yv * yv;                        // wave sums fit in int32
        #pragma unroll
        for (int off = 32; off > 0; off >>= 1) {
            rs += __shfl_down(rs, off);
            rq += __shfl_down(rq, off);
        }
        if ((threadIdx.x & 63) == 0) {
            atomicAdd(&ssum[co], (u64)(long long)rs);     // 2's-complement wrap = signed sum
            atomicAdd(&ssq[co],  (u64)(long long)rq);
        }
    }
}

// ---------------- per-channel affine from exact integer sums ----------------
__global__ void stats_kernel(const u64* __restrict__ ssum, const u64* __restrict__ ssq,
                             const float* __restrict__ gamma, const float* __restrict__ beta,
                             float2* __restrict__ sc) {
    int c = threadIdx.x;
    double S1 = (double)(long long)ssum[c];
    double S2 = (double)(long long)ssq[c];
    double cnt = 100352.0;
    double mean = S1 / cnt;
    double var = S2 / cnt - mean * mean;
    float a = gamma[c] * rsqrtf((float)var + 1e-5f);
    float b = beta[c] - (float)mean * a;
    sc[c] = make_float2(a, b);
}

// ---------------- normalize + tanh, vectorized ------------------------------
__global__ __launch_bounds__(256) void norm_kernel(const short* __restrict__ y,
                                                   const float2* __restrict__ sc,
                                                   float* __restrict__ out) {
    size_t i = ((size_t)blockIdx.x * 256 + threadIdx.x) * 8;   // 8-groups never cross a plane
    int c = (int)((i / HW) & 255);
    float2 s = sc[c];
    int4 v = *(const int4*)(y + i);
    int vs[4] = {v.x, v.y, v.z, v.w};
    float r[8];
    #pragma unroll
    for (int j = 0; j < 4; ++j) {
        short lo = (short)(vs[j] & 0xffff);
        short hi = (short)(vs[j] >> 16);
        r[2 * j]     = tanhf(s.x * (float)lo + s.y);
        r[2 * j + 1] = tanhf(s.x * (float)hi + s.y);
    }
    *(float4*)(out + i)     = make_float4(r[0], r[1], r[2], r[3]);
    *(float4*)(out + i + 4) = make_float4(r[4], r[5], r[6], r[7]);
}

extern "C" void kernel_launch(void* const* d_in, const int* in_sizes, int n_in,
                              void* d_out, int out_size, void* d_ws, size_t ws_size,
                              hipStream_t stream) {
    const float* x     = (const float*)d_in[0];
    const float* W     = (const float*)d_in[1];
    const float* gamma = (const float*)d_in[2];
    const float* beta  = (const float*)d_in[3];
    float* out = (float*)d_out;

    char* ws = (char*)d_ws;
    short* y   = (short*)ws;                               // 51,380,224 B
    u64*  xp   = (u64*)(ws + 51380224);                    //  3,211,264 B
    u64*  wp   = (u64*)(ws + 54591488);                    //     73,728 B
    u64*  ssum = (u64*)(ws + 54665216);                    //      2,048 B
    u64*  ssq  = ssum + 256;                               //      2,048 B
    float2* sc = (float2*)(ws + 54669312);                 //      2,048 B

    hipMemsetAsync(ssum, 0, 256 * 2 * sizeof(u64), stream);
    pack_w_kernel<<<9, 256, 0, stream>>>(W, wp);
    pack_x_kernel<<<dim3(392, 4), 256, 0, stream>>>(x, xp);
    conv_kernel<<<dim3(392, 4), 256, 0, stream>>>(xp, wp, y, ssum, ssq);
    stats_kernel<<<1, 256, 0, stream>>>(ssum, ssq, gamma, beta, sc);
    norm_kernel<<<12544, 256, 0, stream>>>(y, sc, out);
}

// Round 2
// 296.240 us; speedup vs baseline: 2.7355x; 2.7355x over previous
//
#include <hip/hip_runtime.h>

typedef unsigned long long u64;

#define HW 3136      // 56*56
#define NPIX 100352  // 32*3136

// ---------------- pack weights: [co][kh][kw] -> 4 x u64 (256 ci bits) -------
__global__ __launch_bounds__(256) void pack_w_kernel(const float* __restrict__ W,
                                                     u64* __restrict__ wp) {
    int t = blockIdx.x * 256 + threadIdx.x;   // co*9 + tap, 2304 total (9 blocks)
    int co = t / 9, tap = t % 9;
    u64 b[4] = {0, 0, 0, 0};
    for (int ci = 0; ci < 256; ++ci) {
        float v = W[(size_t)(co * 256 + ci) * 9 + tap];
        if (v >= 0.f) b[ci >> 6] |= 1ull << (ci & 63);
    }
    u64* dst = wp + (size_t)t * 4;
    dst[0] = b[0]; dst[1] = b[1]; dst[2] = b[2]; dst[3] = b[3];
}

// ---------------- pack activations: [n][h][w] -> 4 x u64 --------------------
__global__ __launch_bounds__(256) void pack_x_kernel(const float* __restrict__ x,
                                                     u64* __restrict__ xp) {
    int s = blockIdx.x * 256 + threadIdx.x;   // pixel in [0, 100352)
    int word = blockIdx.y;                    // 0..3 (64 channels each)
    int n = s / HW, hw = s % HW;
    const float* px = x + (size_t)(n * 256 + word * 64) * HW + hw;
    u64 b = 0;
    #pragma unroll 8
    for (int ci = 0; ci < 64; ++ci) {
        float v = px[(size_t)ci * HW];
        if (v >= 0.f) b |= 1ull << ci;
    }
    xp[(size_t)s * 4 + word] = b;
}

// ---------------- XNOR conv (taps in registers, weights in LDS) -------------
__global__ __launch_bounds__(256, 4) void conv_kernel(const u64* __restrict__ xp,
                                                      const u64* __restrict__ wp,
                                                      short* __restrict__ y) {
    __shared__ __align__(16) u64 wlds[64 * 36];      // this block's 64 co weights, 18 KB
    int co0 = blockIdx.y * 64;
    for (int i = threadIdx.x; i < 64 * 36; i += 256)
        wlds[i] = wp[(size_t)co0 * 36 + i];
    __syncthreads();

    int s = blockIdx.x * 256 + threadIdx.x;   // pixel
    int n = s / HW, hw = s % HW;
    int h = hw / 56, w = hw % 56;

    u64 xv[9][4];
    int mask9 = 0;
    #pragma unroll
    for (int kh = 0; kh < 3; ++kh) {
        int hh = h + 2 * kh - 2;
        int hc = hh < 0 ? 0 : (hh > 55 ? 55 : hh);
        #pragma unroll
        for (int kw = 0; kw < 3; ++kw) {
            int ww = w + 2 * kw - 2;
            int wc = ww < 0 ? 0 : (ww > 55 ? 55 : ww);
            int t = kh * 3 + kw;
            const u64* p = xp + ((size_t)(n * HW) + hc * 56 + wc) * 4;
            xv[t][0] = p[0]; xv[t][1] = p[1]; xv[t][2] = p[2]; xv[t][3] = p[3];
            if (hh == hc && ww == wc) mask9 |= 1 << t;   // in-bounds tap
        }
    }
    int base = 256 * __popc(mask9);

    short* yo = y + (size_t)(n * 256 + co0) * HW + hw;
    for (int cl = 0; cl < 64; ++cl) {
        const u64* wq = &wlds[cl * 36];        // uniform address -> broadcast reads
        int pacc = 0;
        #pragma unroll
        for (int t = 0; t < 9; ++t) {
            int p = __popcll(xv[t][0] ^ wq[t * 4 + 0]) + __popcll(xv[t][1] ^ wq[t * 4 + 1])
                  + __popcll(xv[t][2] ^ wq[t * 4 + 2]) + __popcll(xv[t][3] ^ wq[t * 4 + 3]);
            pacc += ((mask9 >> t) & 1) ? p : 0;
        }
        yo[(size_t)cl * HW] = (short)(base - 2 * pacc);   // exact integer conv result
    }
}

// ---------------- exact per-channel stats -> affine coefficients ------------
__global__ __launch_bounds__(256) void stats_kernel(const short* __restrict__ y,
                                                    const float* __restrict__ gamma,
                                                    const float* __restrict__ beta,
                                                    float2* __restrict__ sc) {
    int c = blockIdx.x;                       // one block per channel
    int tid = threadIdx.x;
    long long s1 = 0, s2 = 0;
    for (int n = 0; n < 32; ++n) {
        const short* p = y + (size_t)(n * 256 + c) * HW;
        for (int i = tid; i < 392; i += 256) {            // 392 short8 per plane
            int4 v = *(const int4*)(p + i * 8);
            int vs[4] = {v.x, v.y, v.z, v.w};
            int a = 0, q = 0;
            #pragma unroll
            for (int j = 0; j < 4; ++j) {
                int lo = (short)(vs[j] & 0xffff);
                int hi = (short)(vs[j] >> 16);
                a += lo + hi;
                q += lo * lo + hi * hi;        // <= 8*2304^2, fits int32
            }
            s1 += a; s2 += q;
        }
    }
    #pragma unroll
    for (int off = 32; off > 0; off >>= 1) {
        s1 += __shfl_down(s1, off);
        s2 += __shfl_down(s2, off);
    }
    __shared__ long long ls1[4], ls2[4];
    if ((tid & 63) == 0) { ls1[tid >> 6] = s1; ls2[tid >> 6] = s2; }
    __syncthreads();
    if (tid == 0) {
        double S1 = (double)(ls1[0] + ls1[1] + ls1[2] + ls1[3]);
        double S2 = (double)(ls2[0] + ls2[1] + ls2[2] + ls2[3]);
        double cnt = 100352.0;
        double mean = S1 / cnt;
        double var = S2 / cnt - mean * mean;
        float a = gamma[c] * rsqrtf((float)var + 1e-5f);
        float b = beta[c] - (float)mean * a;
        sc[c] = make_float2(a, b);
    }
}

// ---------------- normalize + tanh, vectorized ------------------------------
__global__ __launch_bounds__(256) void norm_kernel(const short* __restrict__ y,
                                                   const float2* __restrict__ sc,
                                                   float* __restrict__ out) {
    size_t i = ((size_t)blockIdx.x * 256 + threadIdx.x) * 8;   // 8-groups never cross a plane
    int c = (int)((i / HW) & 255);
    float2 s = sc[c];
    int4 v = *(const int4*)(y + i);
    int vs[4] = {v.x, v.y, v.z, v.w};
    float r[8];
    #pragma unroll
    for (int j = 0; j < 4; ++j) {
        short lo = (short)(vs[j] & 0xffff);
        short hi = (short)(vs[j] >> 16);
        r[2 * j]     = tanhf(s.x * (float)lo + s.y);
        r[2 * j + 1] = tanhf(s.x * (float)hi + s.y);
    }
    *(float4*)(out + i)     = make_float4(r[0], r[1], r[2], r[3]);
    *(float4*)(out + i + 4) = make_float4(r[4], r[5], r[6], r[7]);
}

extern "C" void kernel_launch(void* const* d_in, const int* in_sizes, int n_in,
                              void* d_out, int out_size, void* d_ws, size_t ws_size,
                              hipStream_t stream) {
    const float* x     = (const float*)d_in[0];
    const float* W     = (const float*)d_in[1];
    const float* gamma = (const float*)d_in[2];
    const float* beta  = (const float*)d_in[3];
    float* out = (float*)d_out;

    char* ws = (char*)d_ws;
    short* y   = (short*)ws;                               // 51,380,224 B
    u64*  xp   = (u64*)(ws + 51380224);                    //  3,211,264 B
    u64*  wp   = (u64*)(ws + 54591488);                    //     73,728 B
    float2* sc = (float2*)(ws + 54665216);                 //      2,048 B

    pack_w_kernel<<<9, 256, 0, stream>>>(W, wp);
    pack_x_kernel<<<dim3(392, 4), 256, 0, stream>>>(x, xp);
    conv_kernel<<<dim3(392, 4), 256, 0, stream>>>(xp, wp, y);
    stats_kernel<<<256, 256, 0, stream>>>(y, gamma, beta, sc);
    norm_kernel<<<12544, 256, 0, stream>>>(y, sc, out);
}